// Round 8
// baseline (235.489 us; speedup 1.0000x reference)
//
#include <hip/hip_runtime.h>
#include <hip/hip_bf16.h>
#include <cstddef>
#include <cstdint>

#define NB 16
#define LIN 512
#define DM 384
#define DC 1536
#define MELMAX 4096
#define LN_EPS 1e-5f

typedef __bf16 bf16x8 __attribute__((ext_vector_type(8)));
typedef float f32x4 __attribute__((ext_vector_type(4)));

#define GL2LDS(gp, lp)                                                                \
    __builtin_amdgcn_global_load_lds((const __attribute__((address_space(1))) void*)(gp), \
                                     (__attribute__((address_space(3))) void*)(lp), 16, 0, 0)

__device__ __forceinline__ float wred(float v) {
#pragma unroll
    for (int m = 32; m >= 1; m >>= 1) v += __shfl_xor(v, m, 64);
    return v;
}

__device__ __forceinline__ unsigned short f2bf(float f) {
    __hip_bfloat16 h = __float2bfloat16(f);
    return *reinterpret_cast<unsigned short*>(&h);
}

__device__ __forceinline__ float bf2f(unsigned short u) {
    return __uint_as_float(((unsigned)u) << 16);
}

// ---------------------------------------------------------------- cumsum (per batch, Hillis-Steele)

__global__ void cumsum_kernel(const int* __restrict__ tgt, int* __restrict__ cum) {
    __shared__ int s[LIN];
    const int b = blockIdx.x, tid = threadIdx.x;
    s[tid] = tgt[b * LIN + tid];
    __syncthreads();
    for (int off = 1; off < LIN; off <<= 1) {
        int v = (tid >= off) ? s[tid - off] : 0;
        __syncthreads();
        s[tid] += v;
        __syncthreads();
    }
    cum[b * LIN + tid] = s[tid];
}

// ---------------------------------------------------------------- length-regulate gather (standalone)

__global__ __launch_bounds__(256) void gather_kernel(const float* __restrict__ x,
                                                     const int* __restrict__ cum,
                                                     float* __restrict__ out) {
    const int wid = (blockIdx.x * 256 + threadIdx.x) >> 6;
    const int lane = threadIdx.x & 63;
    const int b = wid >> 12;
    const int t = wid & (MELMAX - 1);
    const int* c = cum + b * LIN;
    const int total = c[LIN - 1];
    float4* orow = reinterpret_cast<float4*>(out + ((size_t)b * MELMAX + t) * DM);
    if (t < total) {
        int lo = 0, hi = LIN;
        while (lo < hi) { int mid = (lo + hi) >> 1; if (c[mid] > t) hi = mid; else lo = mid + 1; }
        const int idx = lo < (LIN - 1) ? lo : (LIN - 1);
        const float4* xrow = reinterpret_cast<const float4*>(x + ((size_t)b * LIN + idx) * DM);
#pragma unroll
        for (int j = 0; j < 2; ++j) {
            const int p = lane + 64 * j;
            if (p < DM / 4) orow[p] = xrow[p];
        }
    } else {
        const float4 z = make_float4(0.f, 0.f, 0.f, 0.f);
#pragma unroll
        for (int j = 0; j < 2; ++j) {
            const int p = lane + 64 * j;
            if (p < DM / 4) orow[p] = z;
        }
    }
}

// ---------------------------------------------------------------- fused prep: zpad + cast_x + wcast (one launch)

#define ZPAD_BLKS 96
#define CASTX_BLKS 3072   // NB*LIN*DM/4/256
#define WCAST_BLKS 2304   // DC*DM/256

__global__ void prep_kernel(const float* __restrict__ x, unsigned short* __restrict__ xb,
                            unsigned short* __restrict__ hbig, unsigned short* __restrict__ h2b,
                            const float* __restrict__ w1, const float* __restrict__ w2,
                            const float* __restrict__ w3, const float* __restrict__ w4,
                            unsigned short* __restrict__ o1, unsigned short* __restrict__ o2,
                            unsigned short* __restrict__ o3, unsigned short* __restrict__ o4) {
    const int bid = blockIdx.x, tid = threadIdx.x;
    if (bid < ZPAD_BLKS) {
        const int buf = bid >> 5, rem = bid & 31;
        const int b = rem >> 1, row = (rem & 1) ? (LIN + 1) : 0;
        unsigned short* p = buf == 0 ? xb : (buf == 1 ? hbig : h2b);
        const int rl = buf == 1 ? DC : DM;
        unsigned short* base = p + ((size_t)b * (LIN + 2) + row) * rl;
        for (int c = tid; c < rl; c += 256) base[c] = 0;
        return;
    }
    if (bid < ZPAD_BLKS + CASTX_BLKS) {
        const int idx = (bid - ZPAD_BLKS) * 256 + tid;
        const float4 v = reinterpret_cast<const float4*>(x)[idx];
        const int e = idx * 4;
        const int b = e / (LIN * DM);
        const int rem = e - b * (LIN * DM);
        const int l = rem / DM;
        const int c = rem - l * DM;
        ushort4 o;
        o.x = f2bf(v.x); o.y = f2bf(v.y); o.z = f2bf(v.z); o.w = f2bf(v.w);
        *reinterpret_cast<ushort4*>(xb + ((size_t)b * (LIN + 2) + l + 1) * DM + c) = o;
        return;
    }
    const int j = bid - ZPAD_BLKS - CASTX_BLKS;
    const int which = j / WCAST_BLKS;
    const int idx = (j - which * WCAST_BLKS) * 256 + tid;   // (co,ci) pair
    const float* w = which == 0 ? w1 : which == 1 ? w2 : which == 2 ? w3 : w4;
    unsigned short* gg = which == 0 ? o1 : which == 1 ? o2 : which == 2 ? o3 : o4;
    const int CI = (which == 0 || which == 2) ? DM : DC;
    const int co = idx / CI, ci = idx - co * CI;
    const float* p = w + (size_t)idx * 3;
    unsigned short* o = gg + (size_t)co * (3 * CI) + ci;
    o[0 * CI] = f2bf(p[0]);
    o[1 * CI] = f2bf(p[1]);
    o[2 * CI] = f2bf(p[2]);
}

// ---------------------------------------------------------------- conv1d(k=3,SAME) as bf16 MFMA GEMM
// Counted-vmcnt 2-deep pipeline + bank-optimal LDS:
//   A: row-major with 2-bit XOR chunk swizzle (chunk ^= row&3), both staged source
//      and read slot — spreads the tap-shifted fragment reads across all 32 banks.
//   B: fragment-major groups (byte = kg*256 + fr*16) — wave reads lane-contiguous 1KB.
// BN=64 for all convs -> LDS 42KB -> 3 blocks/CU. Per-wave stage loads {6,5,5,5}:
// wave-branched vmcnt. T5 setprio around MFMA clusters.

template <int CI, int CO>
__global__ __launch_bounds__(256, 3) void conv_mfma_kernel(const unsigned short* __restrict__ in,
                                                           const unsigned short* __restrict__ wg,
                                                           const float* __restrict__ bias,
                                                           unsigned short* __restrict__ out) {
    constexpr int BM = 128, BN = 64, BK = 32;
    constexpr int KC = CI / BK;             // 12 or 48
    constexpr int AGRP = 9;                 // 144 staged rows (need BM+2)
    constexpr int GPT = BN / 16;            // 4 row-groups per B tap tile
    constexpr int BGRP = 3 * GPT;           // 12
    constexpr int NW_N = BN / 32;           // 2
    constexpr int NT = CO / BN;
    constexpr int NCONV = NB * (LIN / BM) * NT;

    __shared__ __align__(16) unsigned short As[2][AGRP * 512];
    __shared__ __align__(16) unsigned short Bs[2][BGRP * 512];

    const int tid = threadIdx.x;
    const int lane = tid & 63;
    const int wv = tid >> 6;

    // bijective XCD-chunk swizzle (m204); NCONV % 8 == 0
    const int orig = blockIdx.x;
    const int q = NCONV >> 3, xcd = orig & 7, o = orig >> 3;
    const int wgid = xcd * q + o;

    const int mg = wgid / NT;               // m-tile (n fastest)
    const int nt = wgid - mg * NT;
    const int b = mg >> 2;                  // LIN/BM == 4
    const int l0 = (mg & 3) * BM;
    const int n0 = nt * BN;

    const int wr = wv >> 1, wc = wv & 1;    // 2x2 wave grid, wave tile 64x32

    const unsigned short* inb = in + (size_t)b * (LIN + 2) * CI;

    f32x4 acc[4][NW_N];
#pragma unroll
    for (int m = 0; m < 4; ++m)
#pragma unroll
        for (int n = 0; n < NW_N; ++n) acc[m][n] = (f32x4){0.f, 0.f, 0.f, 0.f};

    const int lrow = lane >> 2;             // 0..15 (A staging row-in-group)
    const int lch = lane & 3;               // A staging 16B slot
    const int fr = lane & 15, kg = lane >> 4;

    const unsigned short* aroot = inb + (size_t)l0 * CI;
    const unsigned short* broot = wg + (size_t)n0 * (3 * CI);

    // A source chunk swizzle: LDS slot lch holds global chunk (lch ^ (row&3))
    const int aswz = (lch ^ (lrow & 3)) * 8;
    // B fragment-major source: lane fetches (row = lane&15, chunk = lane>>4)
    const int bfr = lane & 15, bkg = lane >> 4;

#define STAGE(c, kb)                                                                      \
    do {                                                                                  \
        const unsigned short* abase = aroot + (kb) * BK;                                  \
        _Pragma("unroll")                                                                 \
        for (int g = wv; g < AGRP; g += 4)                                                \
            GL2LDS(abase + (size_t)(g * 16 + lrow) * CI + aswz, &As[c][g * 512]);         \
        const unsigned short* bbase = broot + (kb) * BK;                                  \
        _Pragma("unroll")                                                                 \
        for (int g2 = wv; g2 < BGRP; g2 += 4) {                                           \
            const int t = g2 / GPT, gr = g2 - t * GPT;                                    \
            GL2LDS(bbase + (size_t)(gr * 16 + bfr) * (3 * CI) + (size_t)t * CI + bkg * 8, \
                   &Bs[c][g2 * 512]);                                                     \
        }                                                                                 \
    } while (0)

#define COMPUTE(c)                                                                        \
    do {                                                                                  \
        _Pragma("unroll")                                                                 \
        for (int t = 0; t < 3; ++t) {                                                     \
            bf16x8 aF[4], bF[NW_N];                                                       \
            _Pragma("unroll")                                                             \
            for (int m = 0; m < 4; ++m) {                                                 \
                const int r = t + wr * 64 + m * 16 + fr;                                  \
                aF[m] = *reinterpret_cast<const bf16x8*>(                                 \
                    &As[c][r * BK + ((kg ^ (r & 3)) * 8)]);                               \
            }                                                                             \
            _Pragma("unroll")                                                             \
            for (int n = 0; n < NW_N; ++n)                                                \
                bF[n] = *reinterpret_cast<const bf16x8*>(                                 \
                    &Bs[c][(t * GPT + wc * NW_N + n) * 512 + kg * 128 + fr * 8]);         \
            __builtin_amdgcn_s_setprio(1);                                                \
            _Pragma("unroll")                                                             \
            for (int m = 0; m < 4; ++m)                                                   \
                _Pragma("unroll")                                                         \
                for (int n = 0; n < NW_N; ++n)                                            \
                    acc[m][n] =                                                           \
                        __builtin_amdgcn_mfma_f32_16x16x32_bf16(aF[m], bF[n], acc[m][n],  \
                                                                0, 0, 0);                 \
            __builtin_amdgcn_s_setprio(0);                                                \
        }                                                                                 \
    } while (0)

    // ---- 2-deep counted-vmcnt pipeline (per-wave load batch: wv0=6, else 5)
    STAGE(0, 0);
    STAGE(1, 1);
#pragma unroll 1
    for (int kb = 0; kb < KC; ++kb) {
        const int cur = kb & 1;
        if (wv == 0)
            asm volatile("s_waitcnt vmcnt(6)" ::: "memory");
        else
            asm volatile("s_waitcnt vmcnt(5)" ::: "memory");
        __builtin_amdgcn_sched_barrier(0);
        __builtin_amdgcn_s_barrier();          // all waves' buf[cur] loads landed
        __builtin_amdgcn_sched_barrier(0);
        COMPUTE(cur);
        asm volatile("s_waitcnt lgkmcnt(0)" ::: "memory");  // my ds_reads of buf[cur] done
        __builtin_amdgcn_sched_barrier(0);
        __builtin_amdgcn_s_barrier();          // everyone done reading buf[cur]
        __builtin_amdgcn_sched_barrier(0);
        int nk = kb + 2;
        if (nk >= KC) nk -= KC;                // wrap keeps outstanding count uniform
        STAGE(cur, nk);
    }
#undef STAGE
#undef COMPUTE

    // epilogue: bias + ReLU -> bf16; C/D layout col=lane&15, row=(lane>>4)*4+reg
    const int fq = lane >> 4;
    float bv[NW_N];
#pragma unroll
    for (int n = 0; n < NW_N; ++n) bv[n] = bias[n0 + wc * (BN / 2) + n * 16 + fr];
    unsigned short* outb = out + (size_t)b * (LIN + 2) * CO;
#pragma unroll
    for (int m = 0; m < 4; ++m)
#pragma unroll
        for (int qy = 0; qy < 4; ++qy) {
            const int grow = l0 + wr * 64 + m * 16 + fq * 4 + qy + 1;
            unsigned short* orow = outb + (size_t)grow * CO + n0 + wc * (BN / 2) + fr;
#pragma unroll
            for (int n = 0; n < NW_N; ++n) {
                const float v = fmaxf(acc[m][n][qy] + bv[n], 0.f);
                orow[n * 16] = f2bf(v);
            }
        }
}

// ---------------------------------------------------------------- LayerNorm over bf16 padded buffer (in place)

__global__ void ln_kernel(unsigned short* __restrict__ h, const float* __restrict__ g,
                          const float* __restrict__ be) {
    const int row = blockIdx.x, lane = threadIdx.x;
    const int b = row >> 9, l = row & (LIN - 1);
    unsigned short* hr = h + ((size_t)b * (LIN + 2) + l + 1) * DM;
    float v[6];
    float s = 0.f;
#pragma unroll
    for (int j = 0; j < 6; ++j) { v[j] = bf2f(hr[lane + 64 * j]); s += v[j]; }
    s = wred(s);
    const float mean = s * (1.f / DM);
    float vs = 0.f;
#pragma unroll
    for (int j = 0; j < 6; ++j) { const float d = v[j] - mean; vs += d * d; }
    vs = wred(vs);
    const float rstd = rsqrtf(vs * (1.f / DM) + LN_EPS);
#pragma unroll
    for (int j = 0; j < 6; ++j) {
        const int c = lane + 64 * j;
        hr[c] = f2bf((v[j] - mean) * rstd * g[c] + be[c]);
    }
}

// ---------------------------------------------------------------- LayerNorm + linear(384->1), bf16 in, f32 out

__global__ void ln_linear_kernel(const unsigned short* __restrict__ h, const float* __restrict__ g,
                                 const float* __restrict__ be, const float* __restrict__ wl,
                                 const float* __restrict__ bl, float* __restrict__ dur) {
    const int row = blockIdx.x, lane = threadIdx.x;
    const int b = row >> 9, l = row & (LIN - 1);
    const unsigned short* hr = h + ((size_t)b * (LIN + 2) + l + 1) * DM;
    float v[6];
    float s = 0.f;
#pragma unroll
    for (int j = 0; j < 6; ++j) { v[j] = bf2f(hr[lane + 64 * j]); s += v[j]; }
    s = wred(s);
    const float mean = s * (1.f / DM);
    float vs = 0.f;
#pragma unroll
    for (int j = 0; j < 6; ++j) { const float d = v[j] - mean; vs += d * d; }
    vs = wred(vs);
    const float rstd = rsqrtf(vs * (1.f / DM) + LN_EPS);
    float dot = 0.f;
#pragma unroll
    for (int j = 0; j < 6; ++j) {
        const int c = lane + 64 * j;
        dot += ((v[j] - mean) * rstd * g[c] + be[c]) * wl[c];
    }
    dot = wred(dot);
    if (lane == 0) dur[row] = dot + bl[0];
}

// ---------------------------------------------------------------- launch

extern "C" void kernel_launch(void* const* d_in, const int* in_sizes, int n_in,
                              void* d_out, int out_size, void* d_ws, size_t ws_size,
                              hipStream_t stream) {
    const float* x   = (const float*)d_in[0];
    const int*   tgt = (const int*)d_in[1];
    const float* w1  = (const float*)d_in[3];
    const float* b1  = (const float*)d_in[4];
    const float* w2  = (const float*)d_in[5];
    const float* b2  = (const float*)d_in[6];
    const float* g1  = (const float*)d_in[7];
    const float* be1 = (const float*)d_in[8];
    const float* w3  = (const float*)d_in[9];
    const float* b3  = (const float*)d_in[10];
    const float* w4  = (const float*)d_in[11];
    const float* b4  = (const float*)d_in[12];
    const float* g2  = (const float*)d_in[13];
    const float* be2 = (const float*)d_in[14];
    const float* wl  = (const float*)d_in[15];
    const float* bl  = (const float*)d_in[16];

    float* out = (float*)d_out;                         // (16, 4096, 384) f32
    float* dur = out + (size_t)NB * MELMAX * DM;        // (16, 512) f32

    unsigned short* ws = (unsigned short*)d_ws;
    unsigned short* xb   = ws;                                 // (16, 514, 384)  also conv4 out
    unsigned short* hbig = xb + (size_t)NB * (LIN + 2) * DM;   // (16, 514, 1536) conv1/conv3 out
    unsigned short* h2b  = hbig + (size_t)NB * (LIN + 2) * DC; // (16, 514, 384)  conv2 out
    unsigned short* wg1  = h2b + (size_t)NB * (LIN + 2) * DM;  // (1536, 1152)
    unsigned short* wg2  = wg1 + (size_t)DC * 3 * DM;          // (384, 4608)
    unsigned short* wg3  = wg2 + (size_t)DM * 3 * DC;          // (1536, 1152)
    unsigned short* wg4  = wg3 + (size_t)DC * 3 * DM;          // (384, 4608)
    int* cum = (int*)(wg4 + (size_t)DM * 3 * DC);              // (16, 512)

    // ---- output 0: length regulate (standalone — fusion measured slower, R5/R6)
    cumsum_kernel<<<NB, LIN, 0, stream>>>(tgt, cum);
    gather_kernel<<<(NB * MELMAX) / 4, 256, 0, stream>>>(x, cum, out);

    // ---- prep (fused launch)
    prep_kernel<<<ZPAD_BLKS + CASTX_BLKS + 4 * WCAST_BLKS, 256, 0, stream>>>(
        x, xb, hbig, h2b, w1, w2, w3, w4, wg1, wg2, wg3, wg4);

    // ---- output 1: duration predictor (bf16 MFMA convs, counted-vmcnt + bank-optimal LDS)
    conv_mfma_kernel<DM, DC><<<NB * (LIN / 128) * (DC / 64), 256, 0, stream>>>(xb, wg1, b1, hbig);
    conv_mfma_kernel<DC, DM><<<NB * (LIN / 128) * (DM / 64), 256, 0, stream>>>(hbig, wg2, b2, h2b);
    ln_kernel<<<NB * LIN, 64, 0, stream>>>(h2b, g1, be1);
    conv_mfma_kernel<DM, DC><<<NB * (LIN / 128) * (DC / 64), 256, 0, stream>>>(h2b, wg3, b3, hbig);
    conv_mfma_kernel<DC, DM><<<NB * (LIN / 128) * (DM / 64), 256, 0, stream>>>(hbig, wg4, b4, xb);
    ln_linear_kernel<<<NB * LIN, 64, 0, stream>>>(xb, g2, be2, wl, bl, dur);
}

// Round 9
// 232.477 us; speedup vs baseline: 1.0130x; 1.0130x over previous
//
#include <hip/hip_runtime.h>
#include <hip/hip_bf16.h>
#include <cstddef>
#include <cstdint>

#define NB 16
#define LIN 512
#define DM 384
#define DC 1536
#define MELMAX 4096
#define LN_EPS 1e-5f

typedef __bf16 bf16x8 __attribute__((ext_vector_type(8)));
typedef float f32x4 __attribute__((ext_vector_type(4)));

#define GL2LDS(gp, lp)                                                                \
    __builtin_amdgcn_global_load_lds((const __attribute__((address_space(1))) void*)(gp), \
                                     (__attribute__((address_space(3))) void*)(lp), 16, 0, 0)

__device__ __forceinline__ float wred(float v) {
#pragma unroll
    for (int m = 32; m >= 1; m >>= 1) v += __shfl_xor(v, m, 64);
    return v;
}

__device__ __forceinline__ unsigned short f2bf(float f) {
    __hip_bfloat16 h = __float2bfloat16(f);
    return *reinterpret_cast<unsigned short*>(&h);
}

__device__ __forceinline__ float bf2f(unsigned short u) {
    return __uint_as_float(((unsigned)u) << 16);
}

// ---------------------------------------------------------------- cumsum (per batch, Hillis-Steele)

__global__ void cumsum_kernel(const int* __restrict__ tgt, int* __restrict__ cum) {
    __shared__ int s[LIN];
    const int b = blockIdx.x, tid = threadIdx.x;
    s[tid] = tgt[b * LIN + tid];
    __syncthreads();
    for (int off = 1; off < LIN; off <<= 1) {
        int v = (tid >= off) ? s[tid - off] : 0;
        __syncthreads();
        s[tid] += v;
        __syncthreads();
    }
    cum[b * LIN + tid] = s[tid];
}

// ---------------------------------------------------------------- length-regulate gather (standalone)

__global__ __launch_bounds__(256) void gather_kernel(const float* __restrict__ x,
                                                     const int* __restrict__ cum,
                                                     float* __restrict__ out) {
    const int wid = (blockIdx.x * 256 + threadIdx.x) >> 6;
    const int lane = threadIdx.x & 63;
    const int b = wid >> 12;
    const int t = wid & (MELMAX - 1);
    const int* c = cum + b * LIN;
    const int total = c[LIN - 1];
    float4* orow = reinterpret_cast<float4*>(out + ((size_t)b * MELMAX + t) * DM);
    if (t < total) {
        int lo = 0, hi = LIN;
        while (lo < hi) { int mid = (lo + hi) >> 1; if (c[mid] > t) hi = mid; else lo = mid + 1; }
        const int idx = lo < (LIN - 1) ? lo : (LIN - 1);
        const float4* xrow = reinterpret_cast<const float4*>(x + ((size_t)b * LIN + idx) * DM);
#pragma unroll
        for (int j = 0; j < 2; ++j) {
            const int p = lane + 64 * j;
            if (p < DM / 4) orow[p] = xrow[p];
        }
    } else {
        const float4 z = make_float4(0.f, 0.f, 0.f, 0.f);
#pragma unroll
        for (int j = 0; j < 2; ++j) {
            const int p = lane + 64 * j;
            if (p < DM / 4) orow[p] = z;
        }
    }
}

// ---------------------------------------------------------------- fused prep: zpad + cast_x + wcast (one launch)

#define ZPAD_BLKS 96
#define CASTX_BLKS 3072   // NB*LIN*DM/4/256
#define WCAST_BLKS 2304   // DC*DM/256

__global__ void prep_kernel(const float* __restrict__ x, unsigned short* __restrict__ xb,
                            unsigned short* __restrict__ hbig, unsigned short* __restrict__ h2b,
                            const float* __restrict__ w1, const float* __restrict__ w2,
                            const float* __restrict__ w3, const float* __restrict__ w4,
                            unsigned short* __restrict__ o1, unsigned short* __restrict__ o2,
                            unsigned short* __restrict__ o3, unsigned short* __restrict__ o4) {
    const int bid = blockIdx.x, tid = threadIdx.x;
    if (bid < ZPAD_BLKS) {
        const int buf = bid >> 5, rem = bid & 31;
        const int b = rem >> 1, row = (rem & 1) ? (LIN + 1) : 0;
        unsigned short* p = buf == 0 ? xb : (buf == 1 ? hbig : h2b);
        const int rl = buf == 1 ? DC : DM;
        unsigned short* base = p + ((size_t)b * (LIN + 2) + row) * rl;
        for (int c = tid; c < rl; c += 256) base[c] = 0;
        return;
    }
    if (bid < ZPAD_BLKS + CASTX_BLKS) {
        const int idx = (bid - ZPAD_BLKS) * 256 + tid;
        const float4 v = reinterpret_cast<const float4*>(x)[idx];
        const int e = idx * 4;
        const int b = e / (LIN * DM);
        const int rem = e - b * (LIN * DM);
        const int l = rem / DM;
        const int c = rem - l * DM;
        ushort4 o;
        o.x = f2bf(v.x); o.y = f2bf(v.y); o.z = f2bf(v.z); o.w = f2bf(v.w);
        *reinterpret_cast<ushort4*>(xb + ((size_t)b * (LIN + 2) + l + 1) * DM + c) = o;
        return;
    }
    const int j = bid - ZPAD_BLKS - CASTX_BLKS;
    const int which = j / WCAST_BLKS;
    const int idx = (j - which * WCAST_BLKS) * 256 + tid;   // (co,ci) pair
    const float* w = which == 0 ? w1 : which == 1 ? w2 : which == 2 ? w3 : w4;
    unsigned short* gg = which == 0 ? o1 : which == 1 ? o2 : which == 2 ? o3 : o4;
    const int CI = (which == 0 || which == 2) ? DM : DC;
    const int co = idx / CI, ci = idx - co * CI;
    const float* p = w + (size_t)idx * 3;
    unsigned short* o = gg + (size_t)co * (3 * CI) + ci;
    o[0 * CI] = f2bf(p[0]);
    o[1 * CI] = f2bf(p[1]);
    o[2 * CI] = f2bf(p[2]);
}

// ---------------------------------------------------------------- conv1d(k=3,SAME) as bf16 MFMA GEMM
// Counted-vmcnt 2-deep pipeline. NTIL=2 (conv1/3, KC=12): block persists over 2
// consecutive n-tiles — the K-loop runs 2*KC iterations continuously, the wrap
// prefetch stages the next tile's first K-blocks (B-root switched), and a second
// accumulator defers both epilogues past the loop so no stores disturb the vmcnt
// counts. NTIL=1 (conv2/4, KC=48): original single-tile loop.
// Per-wave stage loads {6,5,5,5} -> wave-branched vmcnt. T5 setprio on MFMA.

template <int CI, int CO, int NTIL>
__global__ __launch_bounds__(256, 3) void conv_mfma_kernel(const unsigned short* __restrict__ in,
                                                           const unsigned short* __restrict__ wg,
                                                           const float* __restrict__ bias,
                                                           unsigned short* __restrict__ out) {
    constexpr int BM = 128, BN = 64, BK = 32;
    constexpr int KC = CI / BK;             // 12 or 48
    constexpr int AGRP = 9;                 // 144 staged rows (need BM+2)
    constexpr int GPT = BN / 16;            // 4 row-groups per B tap tile
    constexpr int BGRP = 3 * GPT;           // 12
    constexpr int NW_N = BN / 32;           // 2
    constexpr int NPJ = CO / BN / NTIL;     // n-groups per m (12 or 6)
    constexpr int NCONV = NB * (LIN / BM) * NPJ;
    constexpr int TOTK = NTIL * KC;

    __shared__ __align__(16) unsigned short As[2][AGRP * 512];
    __shared__ __align__(16) unsigned short Bs[2][BGRP * 512];

    const int tid = threadIdx.x;
    const int lane = tid & 63;
    const int wv = tid >> 6;

    // bijective XCD-chunk swizzle (m204); NCONV % 8 == 0
    const int orig = blockIdx.x;
    const int q = NCONV >> 3, xcd = orig & 7, o = orig >> 3;
    const int wgid = xcd * q + o;

    const int mg = wgid / NPJ;              // m-tile (n fastest)
    const int j = wgid - mg * NPJ;
    const int b = mg >> 2;                  // LIN/BM == 4
    const int l0 = (mg & 3) * BM;
    const int n0 = j * (BN * NTIL);

    const int wr = wv >> 1, wc = wv & 1;    // 2x2 wave grid, wave tile 64x32

    const unsigned short* inb = in + (size_t)b * (LIN + 2) * CI;

    f32x4 acc[4][NW_N], acc2[4][NW_N];
#pragma unroll
    for (int m = 0; m < 4; ++m)
#pragma unroll
        for (int n = 0; n < NW_N; ++n) {
            acc[m][n] = (f32x4){0.f, 0.f, 0.f, 0.f};
            acc2[m][n] = (f32x4){0.f, 0.f, 0.f, 0.f};
        }

    const int lrow = lane >> 2;             // 0..15 (A staging row-in-group)
    const int lch = lane & 3;               // A staging 16B slot
    const int fr = lane & 15, kg = lane >> 4;

    const unsigned short* aroot = inb + (size_t)l0 * CI;
    const unsigned short* broot0 = wg + (size_t)n0 * (3 * CI);
    const unsigned short* broot1 = broot0 + (size_t)BN * (3 * CI);

    // A source chunk swizzle: LDS slot lch holds global chunk (lch ^ (row&3))
    const int aswz = (lch ^ (lrow & 3)) * 8;
    // B fragment-major source: lane fetches (row = lane&15, chunk = lane>>4)
    const int bfr = lane & 15, bkg = lane >> 4;

#define STAGE(c, kb, BR)                                                                  \
    do {                                                                                  \
        const unsigned short* abase = aroot + (kb) * BK;                                  \
        _Pragma("unroll")                                                                 \
        for (int g = wv; g < AGRP; g += 4)                                                \
            GL2LDS(abase + (size_t)(g * 16 + lrow) * CI + aswz, &As[c][g * 512]);         \
        const unsigned short* bbase = (BR) + (kb) * BK;                                   \
        _Pragma("unroll")                                                                 \
        for (int g2 = wv; g2 < BGRP; g2 += 4) {                                           \
            const int t = g2 / GPT, gr = g2 - t * GPT;                                    \
            GL2LDS(bbase + (size_t)(gr * 16 + bfr) * (3 * CI) + (size_t)t * CI + bkg * 8, \
                   &Bs[c][g2 * 512]);                                                     \
        }                                                                                 \
    } while (0)

#define COMPUTE(c, ACC)                                                                   \
    do {                                                                                  \
        _Pragma("unroll")                                                                 \
        for (int t = 0; t < 3; ++t) {                                                     \
            bf16x8 aF[4], bF[NW_N];                                                       \
            _Pragma("unroll")                                                             \
            for (int m = 0; m < 4; ++m) {                                                 \
                const int r = t + wr * 64 + m * 16 + fr;                                  \
                aF[m] = *reinterpret_cast<const bf16x8*>(                                 \
                    &As[c][r * BK + ((kg ^ (r & 3)) * 8)]);                               \
            }                                                                             \
            _Pragma("unroll")                                                             \
            for (int n = 0; n < NW_N; ++n)                                                \
                bF[n] = *reinterpret_cast<const bf16x8*>(                                 \
                    &Bs[c][(t * GPT + wc * NW_N + n) * 512 + kg * 128 + fr * 8]);         \
            __builtin_amdgcn_s_setprio(1);                                                \
            _Pragma("unroll")                                                             \
            for (int m = 0; m < 4; ++m)                                                   \
                _Pragma("unroll")                                                         \
                for (int n = 0; n < NW_N; ++n)                                            \
                    ACC[m][n] =                                                           \
                        __builtin_amdgcn_mfma_f32_16x16x32_bf16(aF[m], bF[n], ACC[m][n],  \
                                                                0, 0, 0);                 \
            __builtin_amdgcn_s_setprio(0);                                                \
        }                                                                                 \
    } while (0)

    // ---- 2-deep counted-vmcnt pipeline across NTIL tiles (no stores inside loop)
    STAGE(0, 0, broot0);
    STAGE(1, 1, broot0);
#pragma unroll 1
    for (int kb = 0; kb < TOTK; ++kb) {
        const int cur = kb & 1;
        if (wv == 0)
            asm volatile("s_waitcnt vmcnt(6)" ::: "memory");
        else
            asm volatile("s_waitcnt vmcnt(5)" ::: "memory");
        __builtin_amdgcn_sched_barrier(0);
        __builtin_amdgcn_s_barrier();          // all waves' buf[cur] loads landed
        __builtin_amdgcn_sched_barrier(0);
        if (NTIL == 1 || kb < KC)
            COMPUTE(cur, acc);
        else
            COMPUTE(cur, acc2);
        asm volatile("s_waitcnt lgkmcnt(0)" ::: "memory");  // my ds_reads of buf[cur] done
        __builtin_amdgcn_sched_barrier(0);
        __builtin_amdgcn_s_barrier();          // everyone done reading buf[cur]
        __builtin_amdgcn_sched_barrier(0);
        int nk = kb + 2;
        if (nk >= TOTK) nk -= TOTK;            // tail wrap: dead re-stage keeps counts uniform
        const unsigned short* br = broot0;
        int ak = nk;
        if (NTIL == 2 && nk >= KC) { br = broot1; ak = nk - KC; }
        STAGE(cur, ak, br);
    }
#undef STAGE
#undef COMPUTE

    // epilogue: bias + ReLU -> bf16; C/D layout col=lane&15, row=(lane>>4)*4+reg
    const int fq = lane >> 4;
    unsigned short* outb = out + (size_t)b * (LIN + 2) * CO;
#define EPI(ACC, NBASE)                                                                   \
    do {                                                                                  \
        float bv[NW_N];                                                                   \
        _Pragma("unroll")                                                                 \
        for (int n = 0; n < NW_N; ++n) bv[n] = bias[(NBASE) + wc * (BN / 2) + n * 16 + fr]; \
        _Pragma("unroll")                                                                 \
        for (int m = 0; m < 4; ++m)                                                       \
            _Pragma("unroll")                                                             \
            for (int qy = 0; qy < 4; ++qy) {                                              \
                const int grow = l0 + wr * 64 + m * 16 + fq * 4 + qy + 1;                 \
                unsigned short* orow =                                                    \
                    outb + (size_t)grow * CO + (NBASE) + wc * (BN / 2) + fr;              \
                _Pragma("unroll")                                                         \
                for (int n = 0; n < NW_N; ++n) {                                          \
                    const float v = fmaxf(ACC[m][n][qy] + bv[n], 0.f);                    \
                    orow[n * 16] = f2bf(v);                                               \
                }                                                                         \
            }                                                                             \
    } while (0)

    EPI(acc, n0);
    if (NTIL == 2) EPI(acc2, n0 + BN);
#undef EPI
}

// ---------------------------------------------------------------- LayerNorm over bf16 padded buffer (in place)

__global__ void ln_kernel(unsigned short* __restrict__ h, const float* __restrict__ g,
                          const float* __restrict__ be) {
    const int row = blockIdx.x, lane = threadIdx.x;
    const int b = row >> 9, l = row & (LIN - 1);
    unsigned short* hr = h + ((size_t)b * (LIN + 2) + l + 1) * DM;
    float v[6];
    float s = 0.f;
#pragma unroll
    for (int j = 0; j < 6; ++j) { v[j] = bf2f(hr[lane + 64 * j]); s += v[j]; }
    s = wred(s);
    const float mean = s * (1.f / DM);
    float vs = 0.f;
#pragma unroll
    for (int j = 0; j < 6; ++j) { const float d = v[j] - mean; vs += d * d; }
    vs = wred(vs);
    const float rstd = rsqrtf(vs * (1.f / DM) + LN_EPS);
#pragma unroll
    for (int j = 0; j < 6; ++j) {
        const int c = lane + 64 * j;
        hr[c] = f2bf((v[j] - mean) * rstd * g[c] + be[c]);
    }
}

// ---------------------------------------------------------------- LayerNorm + linear(384->1), bf16 in, f32 out

__global__ void ln_linear_kernel(const unsigned short* __restrict__ h, const float* __restrict__ g,
                                 const float* __restrict__ be, const float* __restrict__ wl,
                                 const float* __restrict__ bl, float* __restrict__ dur) {
    const int row = blockIdx.x, lane = threadIdx.x;
    const int b = row >> 9, l = row & (LIN - 1);
    const unsigned short* hr = h + ((size_t)b * (LIN + 2) + l + 1) * DM;
    float v[6];
    float s = 0.f;
#pragma unroll
    for (int j = 0; j < 6; ++j) { v[j] = bf2f(hr[lane + 64 * j]); s += v[j]; }
    s = wred(s);
    const float mean = s * (1.f / DM);
    float vs = 0.f;
#pragma unroll
    for (int j = 0; j < 6; ++j) { const float d = v[j] - mean; vs += d * d; }
    vs = wred(vs);
    const float rstd = rsqrtf(vs * (1.f / DM) + LN_EPS);
    float dot = 0.f;
#pragma unroll
    for (int j = 0; j < 6; ++j) {
        const int c = lane + 64 * j;
        dot += ((v[j] - mean) * rstd * g[c] + be[c]) * wl[c];
    }
    dot = wred(dot);
    if (lane == 0) dur[row] = dot + bl[0];
}

// ---------------------------------------------------------------- launch

extern "C" void kernel_launch(void* const* d_in, const int* in_sizes, int n_in,
                              void* d_out, int out_size, void* d_ws, size_t ws_size,
                              hipStream_t stream) {
    const float* x   = (const float*)d_in[0];
    const int*   tgt = (const int*)d_in[1];
    const float* w1  = (const float*)d_in[3];
    const float* b1  = (const float*)d_in[4];
    const float* w2  = (const float*)d_in[5];
    const float* b2  = (const float*)d_in[6];
    const float* g1  = (const float*)d_in[7];
    const float* be1 = (const float*)d_in[8];
    const float* w3  = (const float*)d_in[9];
    const float* b3  = (const float*)d_in[10];
    const float* w4  = (const float*)d_in[11];
    const float* b4  = (const float*)d_in[12];
    const float* g2  = (const float*)d_in[13];
    const float* be2 = (const float*)d_in[14];
    const float* wl  = (const float*)d_in[15];
    const float* bl  = (const float*)d_in[16];

    float* out = (float*)d_out;                         // (16, 4096, 384) f32
    float* dur = out + (size_t)NB * MELMAX * DM;        // (16, 512) f32

    unsigned short* ws = (unsigned short*)d_ws;
    unsigned short* xb   = ws;                                 // (16, 514, 384)  also conv4 out
    unsigned short* hbig = xb + (size_t)NB * (LIN + 2) * DM;   // (16, 514, 1536) conv1/conv3 out
    unsigned short* h2b  = hbig + (size_t)NB * (LIN + 2) * DC; // (16, 514, 384)  conv2 out
    unsigned short* wg1  = h2b + (size_t)NB * (LIN + 2) * DM;  // (1536, 1152)
    unsigned short* wg2  = wg1 + (size_t)DC * 3 * DM;          // (384, 4608)
    unsigned short* wg3  = wg2 + (size_t)DM * 3 * DC;          // (1536, 1152)
    unsigned short* wg4  = wg3 + (size_t)DC * 3 * DM;          // (384, 4608)
    int* cum = (int*)(wg4 + (size_t)DM * 3 * DC);              // (16, 512)

    // ---- output 0: length regulate (standalone — fusion measured slower, R5/R6)
    cumsum_kernel<<<NB, LIN, 0, stream>>>(tgt, cum);
    gather_kernel<<<(NB * MELMAX) / 4, 256, 0, stream>>>(x, cum, out);

    // ---- prep (fused launch)
    prep_kernel<<<ZPAD_BLKS + CASTX_BLKS + 4 * WCAST_BLKS, 256, 0, stream>>>(
        x, xb, hbig, h2b, w1, w2, w3, w4, wg1, wg2, wg3, wg4);

    // ---- output 1: duration predictor (bf16 MFMA convs)
    // conv1/3: KC=12 -> 2-n-tile persistent blocks (24-iter pipeline), grid 768
    // conv2/4: KC=48 -> single tile, grid 384
    conv_mfma_kernel<DM, DC, 2><<<NB * (LIN / 128) * (DC / 128), 256, 0, stream>>>(xb, wg1, b1, hbig);
    conv_mfma_kernel<DC, DM, 1><<<NB * (LIN / 128) * (DM / 64), 256, 0, stream>>>(hbig, wg2, b2, h2b);
    ln_kernel<<<NB * LIN, 64, 0, stream>>>(h2b, g1, be1);
    conv_mfma_kernel<DM, DC, 2><<<NB * (LIN / 128) * (DC / 128), 256, 0, stream>>>(h2b, wg3, b3, hbig);
    conv_mfma_kernel<DC, DM, 1><<<NB * (LIN / 128) * (DM / 64), 256, 0, stream>>>(hbig, wg4, b4, xb);
    ln_linear_kernel<<<NB * LIN, 64, 0, stream>>>(xb, g2, be2, wl, bl, dur);
}